// Round 2
// baseline (920.781 us; speedup 1.0000x reference)
//
#include <hip/hip_runtime.h>
#include <hip/hip_bf16.h>

// Problem constants
#define BQ 8
#define NP 1025
#define NH 8
#define HD 64
#define ED 512
#define NTOK (BQ * NP)      // 8200 tokens
#define VT_STRIDE 1088      // padded key-stride for V^T (16B-aligned rows; 17*64=1088)

typedef __attribute__((ext_vector_type(8))) short short8;   // 8 bf16 = 4 VGPRs (MFMA A/B frag)
typedef __attribute__((ext_vector_type(4))) float floatx4;  // MFMA C/D frag

static __device__ __forceinline__ unsigned short f2bf_raw(float f) {
    __hip_bfloat16 h = __float2bfloat16(f);
    return *reinterpret_cast<unsigned short*>(&h);
}

// ---------------------------------------------------------------------------
// Kernel 1: fused QKV projection.  y = x @ W^T + b  (fp32 in, bf16 staged).
// 64x64 tile, 4 waves, mfma_f32_16x16x32_bf16.
// Outputs: Q,K as [BH, NP, 64] bf16;  V transposed as [BH, 64, VT_STRIDE] bf16.
// ---------------------------------------------------------------------------
__global__ __launch_bounds__(256) void qkv_gemm_kernel(
    const float* __restrict__ x,
    const float* __restrict__ Wq, const float* __restrict__ bq,
    const float* __restrict__ Wk, const float* __restrict__ bk,
    const float* __restrict__ Wv, const float* __restrict__ bv,
    __hip_bfloat16* __restrict__ qws, __hip_bfloat16* __restrict__ kws,
    __hip_bfloat16* __restrict__ vtws)
{
    __shared__ __align__(16) unsigned short As[64 * 32];
    __shared__ __align__(16) unsigned short Bs[64 * 32];

    const int t = threadIdx.x;
    const int wave = t >> 6, lane = t & 63;
    const int quad = lane >> 4, l16 = lane & 15;
    const int m0 = blockIdx.x * 64;            // token tile
    const int ng0 = blockIdx.y * 64;           // global output-col tile over 3*512
    const int wsel = ng0 >> 9;                 // 0=Q 1=K 2=V
    const int n0 = ng0 & 511;

    const float* W    = (wsel == 0) ? Wq : (wsel == 1) ? Wk : Wv;
    const float* bias = (wsel == 0) ? bq : (wsel == 1) ? bk : bv;

    floatx4 acc[4];
#pragma unroll
    for (int i = 0; i < 4; i++) acc[i] = (floatx4){0.f, 0.f, 0.f, 0.f};

    for (int k0 = 0; k0 < 512; k0 += 32) {
        // stage 64x32 fp32 -> bf16 LDS: 512 float4 loads over 256 threads (x2)
#pragma unroll
        for (int i = 0; i < 2; i++) {
            int c = t + 256 * i;
            int row = c >> 3, seg = c & 7;        // seg -> 4 consecutive cols
            int ga = min(m0 + row, NTOK - 1);     // clamp tail rows (stores masked)
            float4 av = *(const float4*)(x + (size_t)ga * 512 + k0 + seg * 4);
            ushort4 ap;
            ap.x = f2bf_raw(av.x); ap.y = f2bf_raw(av.y);
            ap.z = f2bf_raw(av.z); ap.w = f2bf_raw(av.w);
            *(ushort4*)(&As[row * 32 + seg * 4]) = ap;
            int gb = n0 + row;                    // always < 512
            float4 bvv = *(const float4*)(W + (size_t)gb * 512 + k0 + seg * 4);
            ushort4 bp;
            bp.x = f2bf_raw(bvv.x); bp.y = f2bf_raw(bvv.y);
            bp.z = f2bf_raw(bvv.z); bp.w = f2bf_raw(bvv.w);
            *(ushort4*)(&Bs[row * 32 + seg * 4]) = bp;
        }
        __syncthreads();

        short8 a = *(const short8*)(&As[(16 * wave + l16) * 32 + quad * 8]);
#pragma unroll
        for (int nt = 0; nt < 4; nt++) {
            short8 bfr = *(const short8*)(&Bs[(nt * 16 + l16) * 32 + quad * 8]);
            acc[nt] = __builtin_amdgcn_mfma_f32_16x16x32_bf16(a, bfr, acc[nt], 0, 0, 0);
        }
        __syncthreads();
    }

    // epilogue: C/D layout row=(quad*4+r), col=l16 per 16x16 tile
#pragma unroll
    for (int nt = 0; nt < 4; nt++) {
        int col = n0 + nt * 16 + l16;
        float bv_ = bias[col];
#pragma unroll
        for (int r = 0; r < 4; r++) {
            int m = m0 + 16 * wave + quad * 4 + r;
            if (m >= NTOK) continue;
            float v = acc[nt][r] + bv_;
            int b = m / NP, np = m - b * NP;
            int h = col >> 6, d = col & 63;
            int bh = b * NH + h;
            __hip_bfloat16 o = __float2bfloat16(v);
            if (wsel == 0)      qws[((size_t)bh * NP + np) * HD + d] = o;
            else if (wsel == 1) kws[((size_t)bh * NP + np) * HD + d] = o;
            else                vtws[((size_t)bh * HD + d) * VT_STRIDE + np] = o;
        }
    }
}

// ---------------------------------------------------------------------------
// Kernel 2: flash attention per (b,h, 64-query tile).  17 key tiles of 64.
// S tile via MFMA (bf16 Q/K), fp32 bias add + mask + online softmax,
// P -> LDS (bf16) -> PV MFMA with V^T tiles.
// ---------------------------------------------------------------------------
__global__ __launch_bounds__(256) void attn_kernel(
    const __hip_bfloat16* __restrict__ qws,
    const __hip_bfloat16* __restrict__ kws,
    const __hip_bfloat16* __restrict__ vtws,
    const float* __restrict__ attn_bias,           // [B,H,NP,NP] fp32
    const int* __restrict__ pad_mask,              // [B,1,1024,1024] int32
    __hip_bfloat16* __restrict__ attnout)          // [B,NP,512] bf16 (ws)
{
    __shared__ __align__(16) unsigned short Qs[64 * 64];
    __shared__ __align__(16) unsigned short Ks[64 * 64];
    __shared__ __align__(16) unsigned short Vs[64 * 64];   // V^T tile: [d][key_local]
    __shared__ __align__(16) unsigned short Ps[64 * 64];

    const int t = threadIdx.x;
    const int wave = t >> 6, lane = t & 63;
    const int quad = lane >> 4, l16 = lane & 15;
    const int q0 = blockIdx.x * 64;
    const int bh = blockIdx.y;
    const int b = bh >> 3, h = bh & 7;

    // stage Q tile (64x64 bf16 = 8KB -> 2 x 16B per thread)
#pragma unroll
    for (int i = 0; i < 2; i++) {
        int c = t + 256 * i;
        int row = c >> 3, seg = c & 7;
        int gq = min(q0 + row, NP - 1);
        *(uint4*)(&Qs[row * 64 + seg * 8]) =
            *(const uint4*)(qws + ((size_t)bh * NP + gq) * HD + seg * 8);
    }

    float m_run[4], l_run[4];
    floatx4 o_acc[4];
#pragma unroll
    for (int r = 0; r < 4; r++) { m_run[r] = -INFINITY; l_run[r] = 0.f; }
#pragma unroll
    for (int nt = 0; nt < 4; nt++) o_acc[nt] = (floatx4){0.f, 0.f, 0.f, 0.f};

    for (int kt = 0; kt < 17; kt++) {
        const int k0 = kt * 64;
        __syncthreads();  // prior iter's LDS reads done (also orders Qs writes at kt=0)
#pragma unroll
        for (int i = 0; i < 2; i++) {
            int c = t + 256 * i;
            int row = c >> 3, seg = c & 7;
            int gk = min(k0 + row, NP - 1);
            *(uint4*)(&Ks[row * 64 + seg * 8]) =
                *(const uint4*)(kws + ((size_t)bh * NP + gk) * HD + seg * 8);
            *(uint4*)(&Vs[row * 64 + seg * 8]) =
                *(const uint4*)(vtws + ((size_t)bh * HD + row) * VT_STRIDE + k0 + seg * 8);
        }
        __syncthreads();

        // S = Q K^T  (A = Q rows, B = K rows, both d-contiguous)
        floatx4 s[4];
#pragma unroll
        for (int nt = 0; nt < 4; nt++) s[nt] = (floatx4){0.f, 0.f, 0.f, 0.f};
#pragma unroll
        for (int kc = 0; kc < 2; kc++) {
            short8 a = *(const short8*)(&Qs[(16 * wave + l16) * 64 + kc * 32 + quad * 8]);
#pragma unroll
            for (int nt = 0; nt < 4; nt++) {
                short8 bb = *(const short8*)(&Ks[(nt * 16 + l16) * 64 + kc * 32 + quad * 8]);
                s[nt] = __builtin_amdgcn_mfma_f32_16x16x32_bf16(a, bb, s[nt], 0, 0, 0);
            }
        }

        // scale + fp32 bias + mask;  track per-row max
        float mx[4] = {-INFINITY, -INFINITY, -INFINITY, -INFINITY};
#pragma unroll
        for (int nt = 0; nt < 4; nt++) {
#pragma unroll
            for (int r = 0; r < 4; r++) {
                int q = q0 + 16 * wave + quad * 4 + r;
                int qc = min(q, NP - 1);
                int col = k0 + nt * 16 + l16;
                float sv;
                if (col >= NP) {
                    sv = -INFINITY;
                } else {
                    sv = s[nt][r] * 0.125f +
                         attn_bias[((size_t)bh * NP + qc) * NP + col];
                    if (qc >= 1 && col >= 1) {
                        if (!pad_mask[((size_t)b * 1024 + (qc - 1)) * 1024 + (col - 1)])
                            sv = -INFINITY;
                    }
                }
                s[nt][r] = sv;
                mx[r] = fmaxf(mx[r], sv);
            }
        }
        // row-max across the 16 lanes sharing each row
#pragma unroll
        for (int r = 0; r < 4; r++) {
            mx[r] = fmaxf(mx[r], __shfl_xor(mx[r], 1));
            mx[r] = fmaxf(mx[r], __shfl_xor(mx[r], 2));
            mx[r] = fmaxf(mx[r], __shfl_xor(mx[r], 4));
            mx[r] = fmaxf(mx[r], __shfl_xor(mx[r], 8));
        }
        float m_new[4], alpha[4], rs[4];
#pragma unroll
        for (int r = 0; r < 4; r++) {
            m_new[r] = fmaxf(m_run[r], mx[r]);
            alpha[r] = (m_run[r] == -INFINITY) ? 0.f : __expf(m_run[r] - m_new[r]);
            rs[r] = 0.f;
        }
        // p = exp(s - m_new); write P tile to LDS (bf16)
#pragma unroll
        for (int nt = 0; nt < 4; nt++) {
#pragma unroll
            for (int r = 0; r < 4; r++) {
                float sv = s[nt][r];
                float p = (sv == -INFINITY) ? 0.f : __expf(sv - m_new[r]);
                rs[r] += p;
                Ps[(16 * wave + quad * 4 + r) * 64 + nt * 16 + l16] = f2bf_raw(p);
            }
        }
#pragma unroll
        for (int r = 0; r < 4; r++) {
            rs[r] += __shfl_xor(rs[r], 1);
            rs[r] += __shfl_xor(rs[r], 2);
            rs[r] += __shfl_xor(rs[r], 4);
            rs[r] += __shfl_xor(rs[r], 8);
            l_run[r] = l_run[r] * alpha[r] + rs[r];
            m_run[r] = m_new[r];
        }
        // rescale O accumulator
#pragma unroll
        for (int nt = 0; nt < 4; nt++)
#pragma unroll
            for (int r = 0; r < 4; r++) o_acc[nt][r] *= alpha[r];

        __syncthreads();  // Ps LDS writes drained before MFMA reads

        // O += P V   (A = P rows, B = V^T rows = B[n=d][k=key])
#pragma unroll
        for (int kc = 0; kc < 2; kc++) {
            short8 a = *(const short8*)(&Ps[(16 * wave + l16) * 64 + kc * 32 + quad * 8]);
#pragma unroll
            for (int nt = 0; nt < 4; nt++) {
                short8 bb = *(const short8*)(&Vs[(nt * 16 + l16) * 64 + kc * 32 + quad * 8]);
                o_acc[nt] = __builtin_amdgcn_mfma_f32_16x16x32_bf16(a, bb, o_acc[nt], 0, 0, 0);
            }
        }
    }

    // epilogue: attnout[b, q, h*64+d] = O/l  (bf16 workspace)
#pragma unroll
    for (int r = 0; r < 4; r++) {
        int q = q0 + 16 * wave + quad * 4 + r;
        if (q >= NP) continue;
        float inv = 1.f / l_run[r];
#pragma unroll
        for (int nt = 0; nt < 4; nt++) {
            int d = nt * 16 + l16;
            attnout[((size_t)b * NP + q) * ED + h * 64 + d] =
                __float2bfloat16(o_acc[nt][r] * inv);
        }
    }
}

// ---------------------------------------------------------------------------
// Kernel 3: output projection  out = attnout @ Wo^T + bo  -> d_out (fp32)
// ---------------------------------------------------------------------------
__global__ __launch_bounds__(256) void proj_gemm_kernel(
    const __hip_bfloat16* __restrict__ A,     // [8200, 512] bf16 ws
    const float* __restrict__ Wo,
    const float* __restrict__ bo,
    float* __restrict__ out)
{
    __shared__ __align__(16) unsigned short As[64 * 32];
    __shared__ __align__(16) unsigned short Bs[64 * 32];

    const int t = threadIdx.x;
    const int wave = t >> 6, lane = t & 63;
    const int quad = lane >> 4, l16 = lane & 15;
    const int m0 = blockIdx.x * 64;
    const int n0 = blockIdx.y * 64;

    floatx4 acc[4];
#pragma unroll
    for (int i = 0; i < 4; i++) acc[i] = (floatx4){0.f, 0.f, 0.f, 0.f};

    for (int k0 = 0; k0 < 512; k0 += 32) {
        // A tile: bf16 ws, direct 16B copies (64 rows x 2 segs over 256 thr... 64x32 = 2048 elems)
        {
            int row = t >> 2, seg = t & 3;
            int ga = min(m0 + row, NTOK - 1);
            *(uint4*)(&As[row * 32 + seg * 8]) =
                *(const uint4*)(A + (size_t)ga * 512 + k0 + seg * 8);
        }
        // B tile: fp32 -> bf16 convert
#pragma unroll
        for (int i = 0; i < 2; i++) {
            int c = t + 256 * i;
            int row = c >> 3, seg = c & 7;
            int gb = n0 + row;
            float4 bvv = *(const float4*)(Wo + (size_t)gb * 512 + k0 + seg * 4);
            ushort4 bp;
            bp.x = f2bf_raw(bvv.x); bp.y = f2bf_raw(bvv.y);
            bp.z = f2bf_raw(bvv.z); bp.w = f2bf_raw(bvv.w);
            *(ushort4*)(&Bs[row * 32 + seg * 4]) = bp;
        }
        __syncthreads();

        short8 a = *(const short8*)(&As[(16 * wave + l16) * 32 + quad * 8]);
#pragma unroll
        for (int nt = 0; nt < 4; nt++) {
            short8 bfr = *(const short8*)(&Bs[(nt * 16 + l16) * 32 + quad * 8]);
            acc[nt] = __builtin_amdgcn_mfma_f32_16x16x32_bf16(a, bfr, acc[nt], 0, 0, 0);
        }
        __syncthreads();
    }

#pragma unroll
    for (int nt = 0; nt < 4; nt++) {
        int col = n0 + nt * 16 + l16;
        float bv_ = bo[col];
#pragma unroll
        for (int r = 0; r < 4; r++) {
            int m = m0 + 16 * wave + quad * 4 + r;
            if (m >= NTOK) continue;
            out[(size_t)m * ED + col] = acc[nt][r] + bv_;
        }
    }
}

// ---------------------------------------------------------------------------
extern "C" void kernel_launch(void* const* d_in, const int* in_sizes, int n_in,
                              void* d_out, int out_size, void* d_ws, size_t ws_size,
                              hipStream_t stream) {
    (void)in_sizes; (void)n_in; (void)out_size; (void)ws_size;
    const float* x         = (const float*)d_in[0];
    const float* attn_bias = (const float*)d_in[1];
    const int*   pad_mask  = (const int*)d_in[2];
    const float* Wq = (const float*)d_in[3];
    const float* bq = (const float*)d_in[4];
    const float* Wk = (const float*)d_in[5];
    const float* bk = (const float*)d_in[6];
    const float* Wv = (const float*)d_in[7];
    const float* bv = (const float*)d_in[8];
    const float* Wo = (const float*)d_in[9];
    const float* bo = (const float*)d_in[10];
    float* out = (float*)d_out;

    // workspace layout (bytes)
    char* ws = (char*)d_ws;
    const size_t QK_BYTES = (size_t)BQ * NH * NP * HD * 2;        // 8,396,800
    const size_t VT_BYTES = (size_t)BQ * NH * HD * VT_STRIDE * 2; // 8,912,896
    __hip_bfloat16* qws     = (__hip_bfloat16*)(ws);
    __hip_bfloat16* kws     = (__hip_bfloat16*)(ws + QK_BYTES);
    __hip_bfloat16* vtws    = (__hip_bfloat16*)(ws + 2 * QK_BYTES);
    __hip_bfloat16* attnout = (__hip_bfloat16*)(ws + 2 * QK_BYTES + VT_BYTES);

    qkv_gemm_kernel<<<dim3(129, 24), 256, 0, stream>>>(
        x, Wq, bq, Wk, bk, Wv, bv, qws, kws, vtws);
    attn_kernel<<<dim3(17, 64), 256, 0, stream>>>(
        qws, kws, vtws, attn_bias, pad_mask, attnout);
    proj_gemm_kernel<<<dim3(129, 8), 256, 0, stream>>>(
        attnout, Wo, bo, out);
}

// Round 3
// 597.462 us; speedup vs baseline: 1.5412x; 1.5412x over previous
//
#include <hip/hip_runtime.h>
#include <hip/hip_bf16.h>

// Problem constants
#define BQ 8
#define NP 1025
#define NH 8
#define HD 64
#define ED 512
#define NTOK (BQ * NP)      // 8200 tokens
#define VT_STRIDE 1088      // padded key-stride for V^T (16B-aligned; 17*64=1088)
#define LDP 72              // padded LDS row stride in shorts (144 B, 16B-aligned)

typedef __attribute__((ext_vector_type(8))) short short8;   // 8 bf16 (MFMA A/B frag)
typedef __attribute__((ext_vector_type(4))) float floatx4;  // MFMA C/D frag

static __device__ __forceinline__ unsigned short f2bf_raw(float f) {
    __hip_bfloat16 h = __float2bfloat16(f);
    return *reinterpret_cast<unsigned short*>(&h);
}

// ---------------------------------------------------------------------------
// Kernel 0: fp32 -> bf16 convert for x and the four weight matrices.
// wbf layout: rows [0,512)=Wq, [512,1024)=Wk, [1024,1536)=Wv, [1536,2048)=Wo.
// ---------------------------------------------------------------------------
__global__ __launch_bounds__(256) void cvt_kernel(
    const float* __restrict__ x,
    const float* __restrict__ Wq, const float* __restrict__ Wk,
    const float* __restrict__ Wv, const float* __restrict__ Wo,
    unsigned short* __restrict__ xbf, unsigned short* __restrict__ wbf)
{
    const int X4 = (NTOK * ED) / 4;       // 1,049,600 float4s
    const int W4 = (512 * 512) / 4;       // 65,536 = 2^16
    const int total = X4 + 4 * W4;
    for (int i = blockIdx.x * 256 + threadIdx.x; i < total; i += gridDim.x * 256) {
        float4 v; ushort4* dstp;
        if (i < X4) {
            v = ((const float4*)x)[i];
            dstp = ((ushort4*)xbf) + i;
        } else {
            int j = i - X4;
            int sel = j >> 16;
            int lo = j & 65535;
            const float4* s = (const float4*)((sel == 0) ? Wq : (sel == 1) ? Wk
                                           : (sel == 2) ? Wv : Wo);
            v = s[lo];
            dstp = ((ushort4*)wbf) + j;
        }
        ushort4 o;
        o.x = f2bf_raw(v.x); o.y = f2bf_raw(v.y);
        o.z = f2bf_raw(v.z); o.w = f2bf_raw(v.w);
        *dstp = o;
    }
}

// ---------------------------------------------------------------------------
// Kernel 1: fused QKV projection (bf16 NT GEMM, 64x64 tile, reg-prefetch
// pipeline).  Outputs: Q,K [BH,NP,64] bf16; V^T [BH,64,VT_STRIDE] bf16.
// ---------------------------------------------------------------------------
__global__ __launch_bounds__(256) void qkv_gemm_kernel(
    const unsigned short* __restrict__ xbf,   // [NTOK,512]
    const unsigned short* __restrict__ wbf,   // [1536,512] (Q,K,V rows)
    const float* __restrict__ bq, const float* __restrict__ bk,
    const float* __restrict__ bv,
    __hip_bfloat16* __restrict__ qws, __hip_bfloat16* __restrict__ kws,
    __hip_bfloat16* __restrict__ vtws)
{
    __shared__ __align__(16) unsigned short As[64 * 32];
    __shared__ __align__(16) unsigned short Bs[64 * 32];

    const int t = threadIdx.x;
    const int wave = t >> 6, lane = t & 63;
    const int quad = lane >> 4, l16 = lane & 15;
    const int m0 = blockIdx.x * 64;
    const int ng0 = blockIdx.y * 64;          // [0,1536)

    const int arow = t >> 2, aseg = (t & 3) * 8;
    const int ga = min(m0 + arow, NTOK - 1);
    const int gb = ng0 + arow;                // < 1536
    const unsigned short* aptr = xbf + (size_t)ga * 512 + aseg;
    const unsigned short* bptr = wbf + (size_t)gb * 512 + aseg;

    floatx4 acc[4];
#pragma unroll
    for (int i = 0; i < 4; i++) acc[i] = (floatx4){0.f, 0.f, 0.f, 0.f};

    uint4 ar = *(const uint4*)aptr;
    uint4 br = *(const uint4*)bptr;
    for (int s = 0; s < 16; s++) {
        __syncthreads();
        *(uint4*)&As[arow * 32 + aseg] = ar;
        *(uint4*)&Bs[arow * 32 + aseg] = br;
        if (s < 15) {
            ar = *(const uint4*)(aptr + (s + 1) * 32);
            br = *(const uint4*)(bptr + (s + 1) * 32);
        }
        __syncthreads();
        short8 a = *(const short8*)&As[(16 * wave + l16) * 32 + quad * 8];
#pragma unroll
        for (int nt = 0; nt < 4; nt++) {
            short8 bb = *(const short8*)&Bs[(nt * 16 + l16) * 32 + quad * 8];
            acc[nt] = __builtin_amdgcn_mfma_f32_16x16x32_bf16(a, bb, acc[nt], 0, 0, 0);
        }
    }

    const int wsel = ng0 >> 9;
    const float* bias = (wsel == 0) ? bq : (wsel == 1) ? bk : bv;
#pragma unroll
    for (int nt = 0; nt < 4; nt++) {
        int col = ng0 + nt * 16 + l16;
        int lcol = col & 511;
        float bvv = bias[lcol];
#pragma unroll
        for (int r = 0; r < 4; r++) {
            int m = m0 + 16 * wave + quad * 4 + r;
            if (m >= NTOK) continue;
            float v = acc[nt][r] + bvv;
            int b = m / NP, np = m - b * NP;
            int h = lcol >> 6, d = lcol & 63;
            int bh = b * NH + h;
            __hip_bfloat16 o = __float2bfloat16(v);
            if (wsel == 0)      qws[((size_t)bh * NP + np) * HD + d] = o;
            else if (wsel == 1) kws[((size_t)bh * NP + np) * HD + d] = o;
            else                vtws[((size_t)bh * HD + d) * VT_STRIDE + np] = o;
        }
    }
}

// ---------------------------------------------------------------------------
// Kernel 2: flash attention, software-pipelined.
//   - K/V tile kt+1 prefetched to regs during compute of kt
//   - bias/mask tile kt+1 prefetched to regs (consumed next iter)
//   - Q frags in registers (no LDS), Ps write->read same-wave (no barrier)
//   - LDS rows padded to 72 shorts
// ---------------------------------------------------------------------------
__global__ __launch_bounds__(256, 3) void attn_kernel(
    const __hip_bfloat16* __restrict__ qws,
    const __hip_bfloat16* __restrict__ kws,
    const __hip_bfloat16* __restrict__ vtws,
    const float* __restrict__ attn_bias,           // [B,H,NP,NP] fp32
    const int* __restrict__ pad_mask,              // [B,1,1024,1024] int32
    __hip_bfloat16* __restrict__ attnout)          // [B,NP,512] bf16 (ws)
{
    __shared__ __align__(16) unsigned short Ks[64 * LDP];
    __shared__ __align__(16) unsigned short Vs[64 * LDP];
    __shared__ __align__(16) unsigned short Ps[64 * LDP];

    const int t = threadIdx.x;
    const int wave = t >> 6, lane = t & 63;
    const int quad = lane >> 4, l16 = lane & 15;
    const int q0 = blockIdx.x * 64;
    const int bh = blockIdx.y;
    const int b = bh >> 3, h = bh & 7;

    // staging coords: each thread covers rows r0,r1 (16B segment sg)
    const int r0 = t >> 3, r1 = 32 + (t >> 3);
    const int sg = (t & 7) * 8;

    // Q fragments: rows 16*wave+l16, cols quad*8 (+32)
    const int qrow = min(q0 + 16 * wave + l16, NP - 1);
    const unsigned short* qb = (const unsigned short*)qws + ((size_t)bh * NP + qrow) * HD;
    short8 qf0 = *(const short8*)(qb + quad * 8);
    short8 qf1 = *(const short8*)(qb + 32 + quad * 8);

    // C-layout row indices (per r), clamped
    int qr[4];
#pragma unroll
    for (int r = 0; r < 4; r++) qr[r] = min(q0 + 16 * wave + quad * 4 + r, NP - 1);

#define LOADBM(B_, M_, K0_) do {                                              \
    _Pragma("unroll") for (int nt = 0; nt < 4; nt++) {                        \
        _Pragma("unroll") for (int r = 0; r < 4; r++) {                       \
            int j = nt * 4 + r;                                               \
            int coln = (K0_) + nt * 16 + l16;                                 \
            int colc = min(coln, 1024);                                       \
            B_[j] = attn_bias[((size_t)bh * NP + qr[r]) * NP + colc];         \
            M_[j] = (qr[r] >= 1 && coln >= 1 && coln <= 1024)                 \
                    ? pad_mask[((size_t)b * 1024 + (qr[r] - 1)) * 1024 + (coln - 1)] \
                    : 1;                                                      \
        } } } while (0)

    // preload: K/V tile 0 -> LDS, bias/mask tile 0 -> regs
    {
        int gk0 = min(r0, NP - 1), gk1 = min(r1, NP - 1);
        *(uint4*)&Ks[r0 * LDP + sg] = *(const uint4*)(kws + ((size_t)bh * NP + gk0) * HD + sg);
        *(uint4*)&Ks[r1 * LDP + sg] = *(const uint4*)(kws + ((size_t)bh * NP + gk1) * HD + sg);
        *(uint4*)&Vs[r0 * LDP + sg] = *(const uint4*)(vtws + ((size_t)bh * HD + r0) * VT_STRIDE + sg);
        *(uint4*)&Vs[r1 * LDP + sg] = *(const uint4*)(vtws + ((size_t)bh * HD + r1) * VT_STRIDE + sg);
    }
    float bias_c[16]; int msk_c[16];
    LOADBM(bias_c, msk_c, 0);
    __syncthreads();

    float m_run[4], l_run[4];
    floatx4 o_acc[4];
#pragma unroll
    for (int r = 0; r < 4; r++) { m_run[r] = -3.0e38f; l_run[r] = 0.f; }
#pragma unroll
    for (int nt = 0; nt < 4; nt++) o_acc[nt] = (floatx4){0.f, 0.f, 0.f, 0.f};

    for (int kt = 0; kt < 17; kt++) {
        const int k0 = kt * 64;

        // ---- prefetch next tile (K/V -> regs, bias/mask -> regs) ----
        uint4 kr0, kr1, vr0, vr1;
        float bias_n[16]; int msk_n[16];
        if (kt < 16) {
            const int k0n = k0 + 64;
            int gk0 = min(k0n + r0, NP - 1), gk1 = min(k0n + r1, NP - 1);
            kr0 = *(const uint4*)(kws + ((size_t)bh * NP + gk0) * HD + sg);
            kr1 = *(const uint4*)(kws + ((size_t)bh * NP + gk1) * HD + sg);
            vr0 = *(const uint4*)(vtws + ((size_t)bh * HD + r0) * VT_STRIDE + k0n + sg);
            vr1 = *(const uint4*)(vtws + ((size_t)bh * HD + r1) * VT_STRIDE + k0n + sg);
            LOADBM(bias_n, msk_n, k0n);
        }

        // ---- S = Q K^T ----
        floatx4 s4[4];
#pragma unroll
        for (int nt = 0; nt < 4; nt++) s4[nt] = (floatx4){0.f, 0.f, 0.f, 0.f};
#pragma unroll
        for (int kc = 0; kc < 2; kc++) {
            short8 a = kc ? qf1 : qf0;
#pragma unroll
            for (int nt = 0; nt < 4; nt++) {
                short8 bb = *(const short8*)&Ks[(nt * 16 + l16) * LDP + kc * 32 + quad * 8];
                s4[nt] = __builtin_amdgcn_mfma_f32_16x16x32_bf16(a, bb, s4[nt], 0, 0, 0);
            }
        }

        // ---- scale + bias + mask (regs from previous iter) ----
        float mx[4] = {-3.0e38f, -3.0e38f, -3.0e38f, -3.0e38f};
#pragma unroll
        for (int nt = 0; nt < 4; nt++) {
#pragma unroll
            for (int r = 0; r < 4; r++) {
                int j = nt * 4 + r;
                int col = k0 + nt * 16 + l16;
                float sv = s4[nt][r] * 0.125f + bias_c[j];
                if (col > 1024 || msk_c[j] == 0) sv = -3.0e38f;
                s4[nt][r] = sv;
                mx[r] = fmaxf(mx[r], sv);
            }
        }
#pragma unroll
        for (int r = 0; r < 4; r++) {
            mx[r] = fmaxf(mx[r], __shfl_xor(mx[r], 1));
            mx[r] = fmaxf(mx[r], __shfl_xor(mx[r], 2));
            mx[r] = fmaxf(mx[r], __shfl_xor(mx[r], 4));
            mx[r] = fmaxf(mx[r], __shfl_xor(mx[r], 8));
        }
        float m_new[4], alpha[4], rs[4];
#pragma unroll
        for (int r = 0; r < 4; r++) {
            m_new[r] = fmaxf(m_run[r], mx[r]);
            alpha[r] = __expf(m_run[r] - m_new[r]);   // m_run=-3e38 start -> 0
            rs[r] = 0.f;
        }
#pragma unroll
        for (int nt = 0; nt < 4; nt++) {
#pragma unroll
            for (int r = 0; r < 4; r++) {
                float p = __expf(s4[nt][r] - m_new[r]);   // masked -> exp(-huge)=0
                rs[r] += p;
                Ps[(16 * wave + quad * 4 + r) * LDP + nt * 16 + l16] = f2bf_raw(p);
            }
        }
#pragma unroll
        for (int r = 0; r < 4; r++) {
            rs[r] += __shfl_xor(rs[r], 1);
            rs[r] += __shfl_xor(rs[r], 2);
            rs[r] += __shfl_xor(rs[r], 4);
            rs[r] += __shfl_xor(rs[r], 8);
            l_run[r] = l_run[r] * alpha[r] + rs[r];
            m_run[r] = m_new[r];
        }
#pragma unroll
        for (int nt = 0; nt < 4; nt++)
#pragma unroll
            for (int r = 0; r < 4; r++) o_acc[nt][r] *= alpha[r];

        // ---- O += P V  (Ps write->read is same-wave rows; DS in-order) ----
#pragma unroll
        for (int kc = 0; kc < 2; kc++) {
            short8 a = *(const short8*)&Ps[(16 * wave + l16) * LDP + kc * 32 + quad * 8];
#pragma unroll
            for (int nt = 0; nt < 4; nt++) {
                short8 bb = *(const short8*)&Vs[(nt * 16 + l16) * LDP + kc * 32 + quad * 8];
                o_acc[nt] = __builtin_amdgcn_mfma_f32_16x16x32_bf16(a, bb, o_acc[nt], 0, 0, 0);
            }
        }

        // ---- stage prefetched K/V into LDS for next iter ----
        if (kt < 16) {
            __syncthreads();
            *(uint4*)&Ks[r0 * LDP + sg] = kr0;
            *(uint4*)&Ks[r1 * LDP + sg] = kr1;
            *(uint4*)&Vs[r0 * LDP + sg] = vr0;
            *(uint4*)&Vs[r1 * LDP + sg] = vr1;
            __syncthreads();
#pragma unroll
            for (int j = 0; j < 16; j++) { bias_c[j] = bias_n[j]; msk_c[j] = msk_n[j]; }
        }
    }

    // epilogue
#pragma unroll
    for (int r = 0; r < 4; r++) {
        int q = q0 + 16 * wave + quad * 4 + r;
        if (q >= NP) continue;
        float inv = 1.f / l_run[r];
#pragma unroll
        for (int nt = 0; nt < 4; nt++) {
            int d = nt * 16 + l16;
            attnout[((size_t)b * NP + q) * ED + h * 64 + d] =
                __float2bfloat16(o_acc[nt][r] * inv);
        }
    }
#undef LOADBM
}

// ---------------------------------------------------------------------------
// Kernel 3: output projection  out = attnout @ Wo^T + bo  (fp32 out)
// ---------------------------------------------------------------------------
__global__ __launch_bounds__(256) void proj_gemm_kernel(
    const unsigned short* __restrict__ A,     // [8200,512] bf16 ws
    const unsigned short* __restrict__ wobf,  // [512,512] bf16
    const float* __restrict__ bo,
    float* __restrict__ out)
{
    __shared__ __align__(16) unsigned short As[64 * 32];
    __shared__ __align__(16) unsigned short Bs[64 * 32];

    const int t = threadIdx.x;
    const int wave = t >> 6, lane = t & 63;
    const int quad = lane >> 4, l16 = lane & 15;
    const int m0 = blockIdx.x * 64;
    const int n0 = blockIdx.y * 64;

    const int arow = t >> 2, aseg = (t & 3) * 8;
    const int ga = min(m0 + arow, NTOK - 1);
    const int gb = n0 + arow;                 // < 512
    const unsigned short* aptr = A + (size_t)ga * 512 + aseg;
    const unsigned short* bptr = wobf + (size_t)gb * 512 + aseg;

    floatx4 acc[4];
#pragma unroll
    for (int i = 0; i < 4; i++) acc[i] = (floatx4){0.f, 0.f, 0.f, 0.f};

    uint4 ar = *(const uint4*)aptr;
    uint4 br = *(const uint4*)bptr;
    for (int s = 0; s < 16; s++) {
        __syncthreads();
        *(uint4*)&As[arow * 32 + aseg] = ar;
        *(uint4*)&Bs[arow * 32 + aseg] = br;
        if (s < 15) {
            ar = *(const uint4*)(aptr + (s + 1) * 32);
            br = *(const uint4*)(bptr + (s + 1) * 32);
        }
        __syncthreads();
        short8 a = *(const short8*)&As[(16 * wave + l16) * 32 + quad * 8];
#pragma unroll
        for (int nt = 0; nt < 4; nt++) {
            short8 bb = *(const short8*)&Bs[(nt * 16 + l16) * 32 + quad * 8];
            acc[nt] = __builtin_amdgcn_mfma_f32_16x16x32_bf16(a, bb, acc[nt], 0, 0, 0);
        }
    }

#pragma unroll
    for (int nt = 0; nt < 4; nt++) {
        int col = n0 + nt * 16 + l16;
        float bvv = bo[col];
#pragma unroll
        for (int r = 0; r < 4; r++) {
            int m = m0 + 16 * wave + quad * 4 + r;
            if (m >= NTOK) continue;
            out[(size_t)m * ED + col] = acc[nt][r] + bvv;
        }
    }
}

// ---------------------------------------------------------------------------
extern "C" void kernel_launch(void* const* d_in, const int* in_sizes, int n_in,
                              void* d_out, int out_size, void* d_ws, size_t ws_size,
                              hipStream_t stream) {
    (void)in_sizes; (void)n_in; (void)out_size; (void)ws_size;
    const float* x         = (const float*)d_in[0];
    const float* attn_bias = (const float*)d_in[1];
    const int*   pad_mask  = (const int*)d_in[2];
    const float* Wq = (const float*)d_in[3];
    const float* bq = (const float*)d_in[4];
    const float* Wk = (const float*)d_in[5];
    const float* bk = (const float*)d_in[6];
    const float* Wv = (const float*)d_in[7];
    const float* bv = (const float*)d_in[8];
    const float* Wo = (const float*)d_in[9];
    const float* bo = (const float*)d_in[10];
    float* out = (float*)d_out;

    // workspace layout (bytes)
    char* ws = (char*)d_ws;
    const size_t XBF_BYTES = (size_t)NTOK * ED * 2;               // 8,396,800
    const size_t WBF_BYTES = (size_t)2048 * 512 * 2;              // 2,097,152
    const size_t QK_BYTES  = (size_t)BQ * NH * NP * HD * 2;       // 8,396,800
    const size_t VT_BYTES  = (size_t)BQ * NH * HD * VT_STRIDE * 2;// 8,912,896
    unsigned short* xbf    = (unsigned short*)(ws);
    unsigned short* wbf    = (unsigned short*)(ws + XBF_BYTES);
    __hip_bfloat16* qws    = (__hip_bfloat16*)(ws + XBF_BYTES + WBF_BYTES);
    __hip_bfloat16* kws    = (__hip_bfloat16*)(ws + XBF_BYTES + WBF_BYTES + QK_BYTES);
    __hip_bfloat16* vtws   = (__hip_bfloat16*)(ws + XBF_BYTES + WBF_BYTES + 2 * QK_BYTES);
    __hip_bfloat16* attnout= (__hip_bfloat16*)(ws + XBF_BYTES + WBF_BYTES + 2 * QK_BYTES + VT_BYTES);

    cvt_kernel<<<2048, 256, 0, stream>>>(x, Wq, Wk, Wv, Wo, xbf, wbf);
    qkv_gemm_kernel<<<dim3(129, 24), 256, 0, stream>>>(
        xbf, wbf, bq, bk, bv, qws, kws, vtws);
    attn_kernel<<<dim3(17, 64), 256, 0, stream>>>(
        qws, kws, vtws, attn_bias, pad_mask, attnout);
    proj_gemm_kernel<<<dim3(129, 8), 256, 0, stream>>>(
        (const unsigned short*)attnout, wbf + (size_t)1536 * 512, bo, out);
}

// Round 4
// 515.297 us; speedup vs baseline: 1.7869x; 1.1595x over previous
//
#include <hip/hip_runtime.h>
#include <hip/hip_bf16.h>

// Problem constants
#define BQ 8
#define NP 1025
#define NH 8
#define HD 64
#define ED 512
#define NTOK (BQ * NP)      // 8200 tokens
#define VT_STRIDE 1088      // padded key-stride for V^T (16B-aligned)
#define LDP 72              // K/V/P LDS row stride in shorts (144 B)
#define BLD 68              // bias LDS row stride in floats (2-way banks = free)
#define MS 1088             // maskb row stride (bytes)
#define NEGBIG -3.0e38f

typedef __attribute__((ext_vector_type(8))) short short8;   // 8 bf16 (MFMA A/B frag)
typedef __attribute__((ext_vector_type(4))) float floatx4;  // MFMA C/D frag

static __device__ __forceinline__ unsigned short f2bf_raw(float f) {
    __hip_bfloat16 h = __float2bfloat16(f);
    return *reinterpret_cast<unsigned short*>(&h);
}

// ---------------------------------------------------------------------------
// Kernel 0: fp32 -> bf16 convert (x, W's) + byte-mask precompute.
// maskb[b][q][k], q,k in [0,1088): 1 = attend. q==0||k==0 -> 1 (graph token),
// k>1024 or q>1024 -> 0, else pad_mask[b][q-1][k-1].
// ---------------------------------------------------------------------------
__global__ __launch_bounds__(256) void cvt_kernel(
    const float* __restrict__ x,
    const float* __restrict__ Wq, const float* __restrict__ Wk,
    const float* __restrict__ Wv, const float* __restrict__ Wo,
    const int* __restrict__ pad,
    unsigned short* __restrict__ xbf, unsigned short* __restrict__ wbf,
    unsigned char* __restrict__ maskb)
{
    const int X4 = (NTOK * ED) / 4;       // 1,049,600
    const int W4 = (512 * 512) / 4;       // 65,536
    const int M4 = BQ * MS * (MS / 4);    // 2,367,488
    const int total = X4 + 4 * W4 + M4;
    for (int i = blockIdx.x * 256 + threadIdx.x; i < total; i += gridDim.x * 256) {
        if (i < X4 + 4 * W4) {
            float4 v; ushort4* dstp;
            if (i < X4) {
                v = ((const float4*)x)[i];
                dstp = ((ushort4*)xbf) + i;
            } else {
                int j = i - X4;
                int sel = j >> 16, lo = j & 65535;
                const float4* s = (const float4*)((sel == 0) ? Wq : (sel == 1) ? Wk
                                               : (sel == 2) ? Wv : Wo);
                v = s[lo];
                dstp = ((ushort4*)wbf) + j;
            }
            ushort4 o;
            o.x = f2bf_raw(v.x); o.y = f2bf_raw(v.y);
            o.z = f2bf_raw(v.z); o.w = f2bf_raw(v.w);
            *dstp = o;
        } else {
            int j = i - X4 - 4 * W4;          // [0, M4)
            int b = j / (MS * (MS / 4));
            int rr = j - b * (MS * (MS / 4));
            int q = rr / (MS / 4);
            int c0 = (rr - q * (MS / 4)) * 4;
            unsigned int outw = 0;
            if (q <= 1024) {
#pragma unroll
                for (int e = 0; e < 4; e++) {
                    int c = c0 + e;
                    unsigned v;
                    if (c > 1024) v = 0;
                    else if (q == 0 || c == 0) v = 1;
                    else v = pad[((size_t)b << 20) + ((size_t)(q - 1) << 10) + (c - 1)] ? 1u : 0u;
                    outw |= v << (8 * e);
                }
            }
            *(unsigned int*)(maskb + ((size_t)b * MS + q) * MS + c0) = outw;
        }
    }
}

// ---------------------------------------------------------------------------
// Kernel 1: fused QKV projection, per-b tiling (grid.x = 8*17).
// Outputs: Q,K [bh][np][64] bf16; V^T [bh][d][VT_STRIDE] bf16 via LDS
// transpose (coalesced 16B global stores, np-aligned).
// ---------------------------------------------------------------------------
__global__ __launch_bounds__(256) void qkv_gemm_kernel(
    const unsigned short* __restrict__ xbf,   // [NTOK,512] bf16
    const unsigned short* __restrict__ wbf,   // [1536,512] bf16 (Wq,Wk,Wv rows)
    const float* __restrict__ bq, const float* __restrict__ bk,
    const float* __restrict__ bv,
    __hip_bfloat16* __restrict__ qws, __hip_bfloat16* __restrict__ kws,
    __hip_bfloat16* __restrict__ vtws)
{
    __shared__ __align__(16) unsigned short As[64 * 32];
    __shared__ __align__(16) unsigned short Bs[64 * 32];
    __shared__ __align__(16) unsigned short Ts[64 * LDP];  // V transpose staging

    const int t = threadIdx.x;
    const int wave = t >> 6, lane = t & 63;
    const int quad = lane >> 4, l16 = lane & 15;
    const int bidx = blockIdx.x;              // 0..135
    const int bb = bidx / 17;
    const int m0 = (bidx % 17) * 64;          // np base
    const int ng0 = blockIdx.y * 64;          // [0,1536)
    const int wsel = ng0 >> 9;
    const int n0 = ng0 & 511;

    const int arow = t >> 2, aseg = (t & 3) * 8;
    const int np_a = min(m0 + arow, NP - 1);
    const unsigned short* aptr = xbf + ((size_t)bb * NP + np_a) * ED + aseg;
    const unsigned short* bptr = wbf + (size_t)(ng0 + arow) * ED + aseg;

    floatx4 acc[4];
#pragma unroll
    for (int i = 0; i < 4; i++) acc[i] = (floatx4){0.f, 0.f, 0.f, 0.f};

    uint4 ar = *(const uint4*)aptr;
    uint4 br = *(const uint4*)bptr;
    for (int s = 0; s < 16; s++) {
        __syncthreads();
        *(uint4*)&As[arow * 32 + aseg] = ar;
        *(uint4*)&Bs[arow * 32 + aseg] = br;
        if (s < 15) {
            ar = *(const uint4*)(aptr + (s + 1) * 32);
            br = *(const uint4*)(bptr + (s + 1) * 32);
        }
        __syncthreads();
        short8 a = *(const short8*)&As[(16 * wave + l16) * 32 + quad * 8];
#pragma unroll
        for (int nt = 0; nt < 4; nt++) {
            short8 bfr = *(const short8*)&Bs[(nt * 16 + l16) * 32 + quad * 8];
            acc[nt] = __builtin_amdgcn_mfma_f32_16x16x32_bf16(a, bfr, acc[nt], 0, 0, 0);
        }
    }

    if (wsel < 2) {
        const float* bias = (wsel == 0) ? bq : bk;
        __hip_bfloat16* dst = (wsel == 0) ? qws : kws;
#pragma unroll
        for (int nt = 0; nt < 4; nt++) {
            int lcol = n0 + nt * 16 + l16;
            float bvv = bias[lcol];
            int hh = lcol >> 6, d = lcol & 63;
            int bh = bb * NH + hh;
#pragma unroll
            for (int r = 0; r < 4; r++) {
                int np = m0 + 16 * wave + quad * 4 + r;
                if (np >= NP) continue;
                dst[((size_t)bh * NP + np) * HD + d] = __float2bfloat16(acc[nt][r] + bvv);
            }
        }
    } else {
        // V: write to LDS transposed, then coalesced global store
#pragma unroll
        for (int nt = 0; nt < 4; nt++) {
            int d = nt * 16 + l16;
            float bvv = bv[n0 + nt * 16 + l16];
#pragma unroll
            for (int r = 0; r < 4; r++) {
                int nploc = 16 * wave + quad * 4 + r;
                Ts[d * LDP + nploc] = f2bf_raw(acc[nt][r] + bvv);
            }
        }
        __syncthreads();
        const int hh = n0 >> 6;
        const size_t vrowbase = (size_t)(bb * NH + hh) * HD;
#pragma unroll
        for (int i = 0; i < 2; i++) {
            int idx = t + 256 * i;
            int d = idx >> 3, seg = idx & 7;
            int npb = m0 + seg * 8;
            __hip_bfloat16* dst = vtws + (vrowbase + d) * VT_STRIDE + npb;
            if (npb + 7 <= NP - 1) {
                *(uint4*)(void*)dst = *(uint4*)&Ts[d * LDP + seg * 8];
            } else {
#pragma unroll
                for (int e = 0; e < 8; e++) {
                    int np = npb + e;
                    if (np < NP) dst[e] = *(__hip_bfloat16*)&Ts[d * LDP + seg * 8 + e];
                }
            }
        }
    }
}

// ---------------------------------------------------------------------------
// Kernel 2: flash attention.  Per iter: 9 wide loads/thread (K/V 4, bias 4,
// mask 1), mask folded into fp32 bias in regs, staged to LDS in the barrier
// window.  Per-lane deferred l-reduction.
// ---------------------------------------------------------------------------
#define LOAD_BIAS(k0v, bmv) do {                                              \
    uint4 mu = *(const uint4*)(mrow + (k0v) + bc0);                           \
    _Pragma("unroll") for (int sgi = 0; sgi < 4; sgi++) {                     \
        int c = (k0v) + bc0 + sgi * 4;                                        \
        float4 f;                                                             \
        if (c + 3 <= NP - 1) f = *(const float4*)(brow + c);                  \
        else if (c == NP - 1) { f.x = brow[NP - 1]; f.y = f.z = f.w = 0.f; }  \
        else { f.x = f.y = f.z = f.w = 0.f; }                                 \
        unsigned mw = ((const unsigned*)&mu)[sgi];                            \
        bmv[sgi * 4 + 0] = (mw & 0xffu)       ? f.x : NEGBIG;                 \
        bmv[sgi * 4 + 1] = (mw & 0xff00u)     ? f.y : NEGBIG;                 \
        bmv[sgi * 4 + 2] = (mw & 0xff0000u)   ? f.z : NEGBIG;                 \
        bmv[sgi * 4 + 3] = (mw & 0xff000000u) ? f.w : NEGBIG;                 \
    } } while (0)

__global__ __launch_bounds__(256, 3) void attn_kernel(
    const __hip_bfloat16* __restrict__ qws,
    const __hip_bfloat16* __restrict__ kws,
    const __hip_bfloat16* __restrict__ vtws,
    const float* __restrict__ attn_bias,           // [B,H,NP,NP] fp32
    const unsigned char* __restrict__ maskb,       // [B,1088,1088] bytes
    __hip_bfloat16* __restrict__ attnout)          // [B,NP,512] bf16 (ws)
{
    __shared__ __align__(16) unsigned short Ks[64 * LDP];
    __shared__ __align__(16) unsigned short Vs[64 * LDP];
    __shared__ __align__(16) unsigned short Ps[64 * LDP];
    __shared__ __align__(16) float Bf[64 * BLD];

    const int t = threadIdx.x;
    const int wave = t >> 6, lane = t & 63;
    const int quad = lane >> 4, l16 = lane & 15;
    const int q0 = blockIdx.x * 64;
    const int bh = blockIdx.y;
    const int b = bh >> 3, h = bh & 7;

    // K/V staging coords
    const int r0 = t >> 3, r1 = 32 + (t >> 3);
    const int sg = (t & 7) * 8;
    const unsigned short* kbase = (const unsigned short*)kws + (size_t)bh * NP * HD;
    const unsigned short* vbase = (const unsigned short*)vtws + (size_t)bh * HD * VT_STRIDE;

    // bias staging coords: row br, 64 cols per 4 threads
    const int br = t >> 2, bc0 = (t & 3) * 16;
    const int qrow_g = min(q0 + br, NP - 1);
    const float* brow = attn_bias + ((size_t)bh * NP + qrow_g) * NP;
    const unsigned char* mrow = maskb + ((size_t)b * MS + qrow_g) * MS;

    // Q fragments in registers
    const int qrow = min(q0 + 16 * wave + l16, NP - 1);
    const unsigned short* qb = (const unsigned short*)qws + ((size_t)bh * NP + qrow) * HD;
    short8 qf0 = *(const short8*)(qb + quad * 8);
    short8 qf1 = *(const short8*)(qb + 32 + quad * 8);

    int qrl[4];
#pragma unroll
    for (int r = 0; r < 4; r++) qrl[r] = 16 * wave + quad * 4 + r;

    // preload tile 0
    {
        int gk0 = min(r0, NP - 1), gk1 = min(r1, NP - 1);
        *(uint4*)&Ks[r0 * LDP + sg] = *(const uint4*)(kbase + (size_t)gk0 * HD + sg);
        *(uint4*)&Ks[r1 * LDP + sg] = *(const uint4*)(kbase + (size_t)gk1 * HD + sg);
        *(uint4*)&Vs[r0 * LDP + sg] = *(const uint4*)(vbase + (size_t)r0 * VT_STRIDE + sg);
        *(uint4*)&Vs[r1 * LDP + sg] = *(const uint4*)(vbase + (size_t)r1 * VT_STRIDE + sg);
        float bm0[16];
        LOAD_BIAS(0, bm0);
#pragma unroll
        for (int sgi = 0; sgi < 4; sgi++)
            *(float4*)&Bf[br * BLD + bc0 + sgi * 4] = *(float4*)&bm0[sgi * 4];
    }
    __syncthreads();

    float m_run[4], l_lane[4];
    floatx4 o_acc[4];
#pragma unroll
    for (int r = 0; r < 4; r++) { m_run[r] = NEGBIG; l_lane[r] = 0.f; }
#pragma unroll
    for (int nt = 0; nt < 4; nt++) o_acc[nt] = (floatx4){0.f, 0.f, 0.f, 0.f};

    for (int kt = 0; kt < 17; kt++) {
        const int k0 = kt * 64;
        const bool nxt = (kt < 16);

        // ---- prefetch next K/V + masked bias into regs ----
        uint4 kr0, kr1, vr0, vr1;
        float bm[16];
        if (nxt) {
            const int k0n = k0 + 64;
            int gk0 = min(k0n + r0, NP - 1), gk1 = min(k0n + r1, NP - 1);
            kr0 = *(const uint4*)(kbase + (size_t)gk0 * HD + sg);
            kr1 = *(const uint4*)(kbase + (size_t)gk1 * HD + sg);
            vr0 = *(const uint4*)(vbase + (size_t)r0 * VT_STRIDE + k0n + sg);
            vr1 = *(const uint4*)(vbase + (size_t)r1 * VT_STRIDE + k0n + sg);
            LOAD_BIAS(k0n, bm);
        }

        // ---- S = Q K^T ----
        floatx4 s4[4];
#pragma unroll
        for (int nt = 0; nt < 4; nt++) s4[nt] = (floatx4){0.f, 0.f, 0.f, 0.f};
#pragma unroll
        for (int kc = 0; kc < 2; kc++) {
            short8 a = kc ? qf1 : qf0;
#pragma unroll
            for (int nt = 0; nt < 4; nt++) {
                short8 bbf = *(const short8*)&Ks[(nt * 16 + l16) * LDP + kc * 32 + quad * 8];
                s4[nt] = __builtin_amdgcn_mfma_f32_16x16x32_bf16(a, bbf, s4[nt], 0, 0, 0);
            }
        }

        // ---- scale + bias (LDS) ; row max ----
        float mx[4] = {NEGBIG, NEGBIG, NEGBIG, NEGBIG};
#pragma unroll
        for (int nt = 0; nt < 4; nt++) {
#pragma unroll
            for (int r = 0; r < 4; r++) {
                float sv = fmaf(s4[nt][r], 0.125f, Bf[qrl[r] * BLD + nt * 16 + l16]);
                s4[nt][r] = sv;
                mx[r] = fmaxf(mx[r], sv);
            }
        }
#pragma unroll
        for (int r = 0; r < 4; r++) {
            mx[r] = fmaxf(mx[r], __shfl_xor(mx[r], 1));
            mx[r] = fmaxf(mx[r], __shfl_xor(mx[r], 2));
            mx[r] = fmaxf(mx[r], __shfl_xor(mx[r], 4));
            mx[r] = fmaxf(mx[r], __shfl_xor(mx[r], 8));
        }
        float m_new[4], alpha[4], rs[4];
#pragma unroll
        for (int r = 0; r < 4; r++) {
            m_new[r] = fmaxf(m_run[r], mx[r]);
            alpha[r] = __expf(m_run[r] - m_new[r]);
            rs[r] = 0.f;
        }
#pragma unroll
        for (int nt = 0; nt < 4; nt++) {
#pragma unroll
            for (int r = 0; r < 4; r++) {
                float p = __expf(s4[nt][r] - m_new[r]);   // masked -> 0
                rs[r] += p;
                Ps[qrl[r] * LDP + nt * 16 + l16] = f2bf_raw(p);
            }
        }
#pragma unroll
        for (int r = 0; r < 4; r++) {
            l_lane[r] = l_lane[r] * alpha[r] + rs[r];     // per-lane partial
            m_run[r] = m_new[r];
        }
#pragma unroll
        for (int nt = 0; nt < 4; nt++)
#pragma unroll
            for (int r = 0; r < 4; r++) o_acc[nt][r] *= alpha[r];

        // ---- O += P V  (same-wave Ps write->read; per-wave DS order) ----
#pragma unroll
        for (int kc = 0; kc < 2; kc++) {
            short8 a = *(const short8*)&Ps[(16 * wave + l16) * LDP + kc * 32 + quad * 8];
#pragma unroll
            for (int nt = 0; nt < 4; nt++) {
                short8 bbf = *(const short8*)&Vs[(nt * 16 + l16) * LDP + kc * 32 + quad * 8];
                o_acc[nt] = __builtin_amdgcn_mfma_f32_16x16x32_bf16(a, bbf, o_acc[nt], 0, 0, 0);
            }
        }

        // ---- stage prefetched tiles into LDS ----
        __syncthreads();
        if (nxt) {
            *(uint4*)&Ks[r0 * LDP + sg] = kr0;
            *(uint4*)&Ks[r1 * LDP + sg] = kr1;
            *(uint4*)&Vs[r0 * LDP + sg] = vr0;
            *(uint4*)&Vs[r1 * LDP + sg] = vr1;
#pragma unroll
            for (int sgi = 0; sgi < 4; sgi++)
                *(float4*)&Bf[br * BLD + bc0 + sgi * 4] = *(float4*)&bm[sgi * 4];
        }
        __syncthreads();
    }

    // epilogue: reduce l across the 16-lane row group, normalize, store
#pragma unroll
    for (int r = 0; r < 4; r++) {
        float lt = l_lane[r];
        lt += __shfl_xor(lt, 1);
        lt += __shfl_xor(lt, 2);
        lt += __shfl_xor(lt, 4);
        lt += __shfl_xor(lt, 8);
        int q = q0 + qrl[r];
        if (q >= NP) continue;
        float inv = 1.f / lt;
#pragma unroll
        for (int nt = 0; nt < 4; nt++) {
            attnout[((size_t)b * NP + q) * ED + h * 64 + nt * 16 + l16] =
                __float2bfloat16(o_acc[nt][r] * inv);
        }
    }
}

// ---------------------------------------------------------------------------
// Kernel 3: output projection  out = attnout @ Wo^T + bo  (fp32 out)
// ---------------------------------------------------------------------------
__global__ __launch_bounds__(256) void proj_gemm_kernel(
    const unsigned short* __restrict__ A,     // [8200,512] bf16 ws
    const unsigned short* __restrict__ wobf,  // [512,512] bf16
    const float* __restrict__ bo,
    float* __restrict__ out)
{
    __shared__ __align__(16) unsigned short As[64 * 32];
    __shared__ __align__(16) unsigned short Bs[64 * 32];

    const int t = threadIdx.x;
    const int wave = t >> 6, lane = t & 63;
    const int quad = lane >> 4, l16 = lane & 15;
    const int m0 = blockIdx.x * 64;
    const int n0 = blockIdx.y * 64;

    const int arow = t >> 2, aseg = (t & 3) * 8;
    const int ga = min(m0 + arow, NTOK - 1);
    const unsigned short* aptr = A + (size_t)ga * 512 + aseg;
    const unsigned short* bptr = wobf + (size_t)(n0 + arow) * 512 + aseg;

    floatx4 acc[4];
#pragma unroll
    for (int i = 0; i < 4; i++) acc[i] = (floatx4){0.f, 0.f, 0.f, 0.f};

    uint4 ar = *(const uint4*)aptr;
    uint4 br = *(const uint4*)bptr;
    for (int s = 0; s < 16; s++) {
        __syncthreads();
        *(uint4*)&As[arow * 32 + aseg] = ar;
        *(uint4*)&Bs[arow * 32 + aseg] = br;
        if (s < 15) {
            ar = *(const uint4*)(aptr + (s + 1) * 32);
            br = *(const uint4*)(bptr + (s + 1) * 32);
        }
        __syncthreads();
        short8 a = *(const short8*)&As[(16 * wave + l16) * 32 + quad * 8];
#pragma unroll
        for (int nt = 0; nt < 4; nt++) {
            short8 bfr = *(const short8*)&Bs[(nt * 16 + l16) * 32 + quad * 8];
            acc[nt] = __builtin_amdgcn_mfma_f32_16x16x32_bf16(a, bfr, acc[nt], 0, 0, 0);
        }
    }

#pragma unroll
    for (int nt = 0; nt < 4; nt++) {
        int col = n0 + nt * 16 + l16;
        float bvv = bo[col];
#pragma unroll
        for (int r = 0; r < 4; r++) {
            int m = m0 + 16 * wave + quad * 4 + r;
            if (m >= NTOK) continue;
            out[(size_t)m * ED + col] = acc[nt][r] + bvv;
        }
    }
}

// ---------------------------------------------------------------------------
extern "C" void kernel_launch(void* const* d_in, const int* in_sizes, int n_in,
                              void* d_out, int out_size, void* d_ws, size_t ws_size,
                              hipStream_t stream) {
    (void)in_sizes; (void)n_in; (void)out_size; (void)ws_size;
    const float* x         = (const float*)d_in[0];
    const float* attn_bias = (const float*)d_in[1];
    const int*   pad_mask  = (const int*)d_in[2];
    const float* Wq = (const float*)d_in[3];
    const float* bq = (const float*)d_in[4];
    const float* Wk = (const float*)d_in[5];
    const float* bk = (const float*)d_in[6];
    const float* Wv = (const float*)d_in[7];
    const float* bv = (const float*)d_in[8];
    const float* Wo = (const float*)d_in[9];
    const float* bo = (const float*)d_in[10];
    float* out = (float*)d_out;

    // workspace layout (bytes); attnout reuses xbf (dead after qkv)
    char* ws = (char*)d_ws;
    const size_t XBF_BYTES = (size_t)NTOK * ED * 2;               // 8,396,800
    const size_t WBF_BYTES = (size_t)2048 * 512 * 2;              // 2,097,152
    const size_t QK_BYTES  = (size_t)BQ * NH * NP * HD * 2;       // 8,396,800
    const size_t VT_BYTES  = (size_t)BQ * NH * HD * VT_STRIDE * 2;// 8,912,896
    unsigned short* xbf    = (unsigned short*)(ws);
    unsigned short* wbf    = (unsigned short*)(ws + XBF_BYTES);
    __hip_bfloat16* qws    = (__hip_bfloat16*)(ws + XBF_BYTES + WBF_BYTES);
    __hip_bfloat16* kws    = (__hip_bfloat16*)(ws + XBF_BYTES + WBF_BYTES + QK_BYTES);
    __hip_bfloat16* vtws   = (__hip_bfloat16*)(ws + XBF_BYTES + WBF_BYTES + 2 * QK_BYTES);
    unsigned char*  maskb  = (unsigned char*)(ws + XBF_BYTES + WBF_BYTES + 2 * QK_BYTES + VT_BYTES);
    __hip_bfloat16* attnout = (__hip_bfloat16*)xbf;   // reuse

    cvt_kernel<<<4096, 256, 0, stream>>>(x, Wq, Wk, Wv, Wo, pad_mask, xbf, wbf, maskb);
    qkv_gemm_kernel<<<dim3(136, 24), 256, 0, stream>>>(
        xbf, wbf, bq, bk, bv, qws, kws, vtws);
    attn_kernel<<<dim3(17, 64), 256, 0, stream>>>(
        qws, kws, vtws, attn_bias, maskb, attnout);
    proj_gemm_kernel<<<dim3(129, 8), 256, 0, stream>>>(
        (const unsigned short*)attnout, wbf + (size_t)1536 * 512, bo, out);
}